// Round 3
// baseline (150.543 us; speedup 1.0000x reference)
//
#include <hip/hip_runtime.h>

#define BN 4
#define CH 64          // CIN*UM = COUT*UM
#define HH 128
#define WW 128
#define PIX (HH*WW)

// workspace layout (float offsets)
#define OFF_WL  0                    // [64][9][64]  = 36864
#define OFF_S   36864                // [2][64]      = 128
#define OFF_CS  36992                // [4][2][128][128] = 131072
#define OFF_AVG 168064               // [4][2][128][128] = 131072

// ---- prep1: blocks [0,144) -> Wl[c][tap][oc];  blocks [144,272) -> colsum (float4)
__global__ __launch_bounds__(256) void k_prep1(const float* __restrict__ params,
                                               const float* __restrict__ basis,
                                               const float* __restrict__ x,
                                               float* __restrict__ Wl,
                                               float* __restrict__ cs) {
    int bx = blockIdx.x;
    if (bx < 144) {
        int idx = bx * 256 + threadIdx.x;      // < 36864
        int oc  = idx & 63;
        int tap = (idx >> 6) % 9;
        int c   = idx / 576;
        int q = tap / 3, p = tap % 3;
        int o = oc >> 1, g = oc & 1;
        int i = c >> 1, u = c & 1;
        float s = 0.f;
        #pragma unroll
        for (int n = 0; n < 4; ++n)
            #pragma unroll
            for (int d = 0; d < 4; ++d)
                s = fmaf(params[((o * 32 + i) * 4 + n) * 4 + d],
                         basis[((((n * 4 + d) * 3 + p) * 3 + q) * 2 + g) * 2 + u], s);
        Wl[idx] = s;
    } else {
        int idx = (bx - 144) * 256 + threadIdx.x;   // < 32768
        int pq  = idx & (PIX / 4 - 1);
        int u   = (idx >> 12) & 1;
        int b   = idx >> 13;
        const float4* xb = (const float4*)x;
        float4 s = make_float4(0.f, 0.f, 0.f, 0.f);
        #pragma unroll
        for (int i = 0; i < 32; ++i) {
            float4 v = xb[(size_t)(b * CH + 2 * i + u) * (PIX / 4) + pq];
            s.x += v.x; s.y += v.y; s.z += v.z; s.w += v.w;
        }
        ((float4*)cs)[(b * 2 + u) * (PIX / 4) + pq] = s;
    }
}

// ---- prep2: blocks [0,128) -> S[u][oc];  blocks [128,640) -> avg = box3x3_edge(cs)/288
__global__ __launch_bounds__(256) void k_prep2(const float* __restrict__ Wl,
                                               const float* __restrict__ cs,
                                               float* __restrict__ S,
                                               float* __restrict__ avg) {
    __shared__ float red[4];
    int bx = blockIdx.x;
    if (bx < 128) {
        int u = bx >> 6, oc = bx & 63;
        int t = threadIdx.x;
        float s = 0.f;
        for (int k = t; k < 288; k += 256) {
            int i = k / 9, tap = k - i * 9;
            s += Wl[((i * 2 + u) * 9 + tap) * 64 + oc];
        }
        #pragma unroll
        for (int o = 32; o; o >>= 1) s += __shfl_down(s, o, 64);
        int lane = t & 63, wv = t >> 6;
        if (lane == 0) red[wv] = s;
        __syncthreads();
        if (t == 0) S[bx] = red[0] + red[1] + red[2] + red[3];
    } else {
        int idx = (bx - 128) * 256 + threadIdx.x;   // < 131072
        int w  = idx & (WW - 1);
        int h  = (idx >> 7) & (HH - 1);
        int bu = idx >> 14;
        const float* c0 = cs + bu * PIX;
        int hm = h > 0 ? h - 1 : 0, hp = h < HH - 1 ? h + 1 : HH - 1;
        int wm = w > 0 ? w - 1 : 0, wp = w < WW - 1 ? w + 1 : WW - 1;
        float s = c0[hm * WW + wm] + c0[hm * WW + w] + c0[hm * WW + wp]
                + c0[h  * WW + wm] + c0[h  * WW + w] + c0[h  * WW + wp]
                + c0[hp * WW + wm] + c0[hp * WW + w] + c0[hp * WW + wp];
        avg[idx] = s * (1.0f / 288.0f);
    }
}

// ---- main: 2 vertical pixels/thread, 16 oc/thread, next-channel x prefetch
__global__ __launch_bounds__(256) void k_main(
    const float* __restrict__ x,     // [4][64][128][128]
    const float* __restrict__ Wl,    // [64][9][64]
    const float* __restrict__ S,     // [2][64]
    const float* __restrict__ bias,  // [64]
    const float* __restrict__ avg,   // [4][2][128][128]
    const float* __restrict__ bptr,  // scalar b
    float* __restrict__ out)         // [4][64][128][128]
{
    int tile   = blockIdx.x;          // 8 w-tiles x 4 h-tiles = 32 ; tile = 16w x 32h
    int ocbase = blockIdx.y * 16;
    int b      = blockIdx.z;
    int tx = threadIdx.x & 15, ty = threadIdx.x >> 4;
    int w  = (tile & 7) * 16 + tx;
    int h0 = (tile >> 3) * 32 + ty * 2;       // rows h0, h0+1

    int rm = h0 > 0 ? h0 - 1 : 0;
    int r3 = (h0 + 2 < HH) ? h0 + 2 : HH - 1;
    int rowoff[4] = { rm * WW, h0 * WW, (h0 + 1) * WW, r3 * WW };
    int wm = w > 0 ? w - 1 : 0, wp = w < WW - 1 ? w + 1 : WW - 1;
    int coloff[3] = { wm, w, wp };

    int off[12];
    #pragma unroll
    for (int r = 0; r < 4; ++r)
        #pragma unroll
        for (int p = 0; p < 3; ++p)
            off[r * 3 + p] = rowoff[r] + coloff[p];

    float acc0[16], acc1[16];
    #pragma unroll
    for (int j = 0; j < 16; ++j) { acc0[j] = 0.f; acc1[j] = 0.f; }

    const float* xc = x + (size_t)b * CH * PIX;
    const float* wc = Wl + ocbase;

    float xv[12];
    #pragma unroll
    for (int k = 0; k < 12; ++k) xv[k] = xc[off[k]];

    for (int c = 0; c < CH; ++c) {
        // prefetch next channel's window (consumed next iteration -> hidden under FMAs)
        const float* xn = xc + (c < CH - 1 ? PIX : 0);
        float xf[12];
        #pragma unroll
        for (int k = 0; k < 12; ++k) xf[k] = xn[off[k]];

        #pragma unroll
        for (int q = 0; q < 3; ++q) {
            #pragma unroll
            for (int p = 0; p < 3; ++p) {
                float x0 = xv[q * 3 + p];           // pixel h0 tap
                float x1 = xv[(q + 1) * 3 + p];     // pixel h0+1 tap
                const float* wt = wc + (q * 3 + p) * 64;
                #pragma unroll
                for (int j = 0; j < 16; ++j) {
                    float wv = wt[j];               // block-uniform -> s_load
                    acc0[j] = fmaf(x0, wv, acc0[j]);
                    acc1[j] = fmaf(x1, wv, acc1[j]);
                }
            }
        }
        #pragma unroll
        for (int k = 0; k < 12; ++k) xv[k] = xf[k];
        xc += PIX;
        wc += 576;
    }

    int pix0 = h0 * WW + w;
    float a0p0 = avg[(b * 2 + 0) * PIX + pix0];
    float a1p0 = avg[(b * 2 + 1) * PIX + pix0];
    float a0p1 = avg[(b * 2 + 0) * PIX + pix0 + WW];
    float a1p1 = avg[(b * 2 + 1) * PIX + pix0 + WW];
    float bthr = bptr[0];

    float* ob = out + (size_t)b * CH * PIX + pix0;
    #pragma unroll
    for (int j = 0; j < 16; j += 2) {
        int oc = ocbase + j;
        float s0 = S[oc], s1 = S[oc + 1];
        float su0 = S[64 + oc], su1 = S[64 + oc + 1];
        float bi0 = bias[oc], bi1 = bias[oc + 1];

        // pixel (h0, w)
        float t0 = acc0[j]     - a0p0 * s0 - a1p0 * su0 + bi0;
        float t1 = acc0[j + 1] - a0p0 * s1 - a1p0 * su1 + bi1;
        float n = sqrtf(t0 * t0 + t1 * t1);
        float r0, r1;
        if (n - bthr <= 0.f) { r0 = 0.f; r1 = 0.f; }
        else { r0 = t0 / n; r1 = t1 / n; }
        ob[(size_t)oc * PIX]       = r0 + a0p0;
        ob[(size_t)(oc + 1) * PIX] = r1 + a1p0;

        // pixel (h0+1, w)
        t0 = acc1[j]     - a0p1 * s0 - a1p1 * su0 + bi0;
        t1 = acc1[j + 1] - a0p1 * s1 - a1p1 * su1 + bi1;
        n = sqrtf(t0 * t0 + t1 * t1);
        if (n - bthr <= 0.f) { r0 = 0.f; r1 = 0.f; }
        else { r0 = t0 / n; r1 = t1 / n; }
        ob[(size_t)oc * PIX + WW]       = r0 + a0p1;
        ob[(size_t)(oc + 1) * PIX + WW] = r1 + a1p1;
    }
}

extern "C" void kernel_launch(void* const* d_in, const int* in_sizes, int n_in,
                              void* d_out, int out_size, void* d_ws, size_t ws_size,
                              hipStream_t stream) {
    const float* xx     = (const float*)d_in[0];
    const float* params = (const float*)d_in[1];
    const float* basis  = (const float*)d_in[2];
    const float* bias   = (const float*)d_in[3];
    const float* bptr   = (const float*)d_in[4];
    float* out = (float*)d_out;
    float* ws  = (float*)d_ws;

    float* Wl  = ws + OFF_WL;
    float* S   = ws + OFF_S;
    float* cs  = ws + OFF_CS;
    float* avg = ws + OFF_AVG;

    k_prep1<<<272, 256, 0, stream>>>(params, basis, xx, Wl, cs);
    k_prep2<<<640, 256, 0, stream>>>(Wl, cs, S, avg);

    dim3 grid(32, 4, BN);
    k_main<<<grid, 256, 0, stream>>>(xx, Wl, S, bias, avg, bptr, out);
}